// Round 15
// baseline (141.371 us; speedup 1.0000x reference)
//
#include <hip/hip_runtime.h>
#include <hip/hip_bf16.h>

// GLA forward, B=4 L=2048 D=1024 H=16 DK=DV=64.
// Round 15: out-GEMM upgraded 4->8 waves (gemm_out8: 128x128/BK=64, wave tile
// 64x32, 512 thr, grid 512 = 2 blocks/CU -> 16 waves/CU, double the TLP of
// r14's gemm_sb128). Everything else identical to r14 (141.3us verified).

typedef __attribute__((ext_vector_type(8))) short s16x8;
typedef __attribute__((ext_vector_type(4))) float f32x4;

#define WIN 5
static const size_t NE = (size_t)8192 * 1024;

__device__ inline void gload16(const void* g, void* lds) {
  __builtin_amdgcn_global_load_lds(
      (const __attribute__((address_space(1))) unsigned int*)g,
      (__attribute__((address_space(3))) unsigned int*)lds, 16, 0, 0);
}

// ---------- QFV: 256x128, BK=64, 8 waves (4M x 2N), SINGLE buffer ----------
// (verified r11-r14: 59.5us, 872 TF, zero bank conflicts, clean traffic)
__global__ __launch_bounds__(512, 2) void gemm_sb(
    const __hip_bfloat16* __restrict__ A, const __hip_bfloat16* __restrict__ Bt,
    __hip_bfloat16* __restrict__ Obf, int K) {
  __shared__ __hip_bfloat16 sa[256 * 64];  // 32 KiB
  __shared__ __hip_bfloat16 sb[128 * 64];  // 16 KiB
  const int tid = threadIdx.x;
  const int lane = tid & 63;
  const int w = tid >> 6;
  const int wm = w >> 1, wn = w & 1;
  const int bm = blockIdx.y * 256, bn = blockIdx.x * 128;

  const int srow = tid >> 3;
  const int scol = ((tid & 7) ^ (srow & 7)) * 8;
  const int r15 = lane & 15, g = lane >> 4;
  const int rx = (r15 & 7) << 4;

  f32x4 acc[4][4] = {};
  const int NT = K / 64;
  for (int t = 0; t < NT; ++t) {
    const int bk = t * 64;
#pragma unroll
    for (int r = 0; r < 4; ++r)
      gload16(A + (size_t)(bm + r * 64 + srow) * K + bk + scol,
              &sa[r * 4096 + tid * 8]);
#pragma unroll
    for (int r = 0; r < 2; ++r)
      gload16(Bt + (size_t)(bn + r * 64 + srow) * K + bk + scol,
              &sb[r * 4096 + tid * 8]);
    __syncthreads();
    s16x8 bfr[4][2], af[4][2];
#pragma unroll
    for (int n = 0; n < 4; ++n)
#pragma unroll
      for (int ks = 0; ks < 2; ++ks)
        bfr[n][ks] = *(const s16x8*)((const char*)sb + (wn * 64 + n * 16 + r15) * 128 +
                                     ((g * 16 + ks * 64) ^ rx));
#pragma unroll
    for (int m = 0; m < 4; ++m)
#pragma unroll
      for (int ks = 0; ks < 2; ++ks)
        af[m][ks] = *(const s16x8*)((const char*)sa + (wm * 64 + m * 16 + r15) * 128 +
                                    ((g * 16 + ks * 64) ^ rx));
#pragma unroll
    for (int m = 0; m < 4; ++m)
#pragma unroll
      for (int n = 0; n < 4; ++n)
#pragma unroll
        for (int ks = 0; ks < 2; ++ks)
          acc[m][n] = __builtin_amdgcn_mfma_f32_16x16x32_bf16(
              af[m][ks], bfr[n][ks], acc[m][n], 0, 0, 0);
    __syncthreads();
  }

  const int rbase = bm + wm * 64 + (lane >> 4) * 4;
#pragma unroll
  for (int m = 0; m < 4; ++m)
#pragma unroll
    for (int n = 0; n < 4; ++n) {
      const int col = bn + wn * 64 + n * 16 + r15;
#pragma unroll
      for (int r = 0; r < 4; ++r)
        Obf[(size_t)(rbase + m * 16 + r) * 3072 + col] = __float2bfloat16(acc[m][n][r]);
    }
}

// ---------- out projection: 128x128, BK=64, 8 waves (2M x 4N), 1 buffer ----
// wave tile 64x32; grid (8,64)=512 = 2 blocks/CU -> 16 waves/CU (4/SIMD).
// Same swizzle algebra: all row offsets (r*64, wm*64, wn*32, n*16) are
// multiples of 8, so row&7 == r15&7 on reads and srow&7 on stores.
__global__ __launch_bounds__(512, 2) void gemm_out8(
    const __hip_bfloat16* __restrict__ A, const __hip_bfloat16* __restrict__ Bt,
    float* __restrict__ C, int K) {
  __shared__ __hip_bfloat16 sa[128 * 64];  // 16 KiB
  __shared__ __hip_bfloat16 sb[128 * 64];  // 16 KiB
  const int tid = threadIdx.x;
  const int lane = tid & 63;
  const int w = tid >> 6;                  // 0..7
  const int wm = w >> 2, wn = w & 3;       // 2M x 4N
  const int bm = blockIdx.y * 128, bn = blockIdx.x * 128;

  const int srow = tid >> 3;               // 0..63 per staging round
  const int scol = ((tid & 7) ^ (srow & 7)) * 8;
  const int r15 = lane & 15, g = lane >> 4;
  const int rx = (r15 & 7) << 4;

  f32x4 acc[4][2] = {};
  const int NT = K / 64;
  for (int t = 0; t < NT; ++t) {
    const int bk = t * 64;
#pragma unroll
    for (int r = 0; r < 2; ++r)
      gload16(A + (size_t)(bm + r * 64 + srow) * K + bk + scol,
              &sa[r * 4096 + tid * 8]);
#pragma unroll
    for (int r = 0; r < 2; ++r)
      gload16(Bt + (size_t)(bn + r * 64 + srow) * K + bk + scol,
              &sb[r * 4096 + tid * 8]);
    __syncthreads();
    s16x8 bfr[2][2], af[4][2];
#pragma unroll
    for (int n = 0; n < 2; ++n)
#pragma unroll
      for (int ks = 0; ks < 2; ++ks)
        bfr[n][ks] = *(const s16x8*)((const char*)sb + (wn * 32 + n * 16 + r15) * 128 +
                                     ((g * 16 + ks * 64) ^ rx));
#pragma unroll
    for (int m = 0; m < 4; ++m)
#pragma unroll
      for (int ks = 0; ks < 2; ++ks)
        af[m][ks] = *(const s16x8*)((const char*)sa + (wm * 64 + m * 16 + r15) * 128 +
                                    ((g * 16 + ks * 64) ^ rx));
#pragma unroll
    for (int m = 0; m < 4; ++m)
#pragma unroll
      for (int n = 0; n < 2; ++n)
#pragma unroll
        for (int ks = 0; ks < 2; ++ks)
          acc[m][n] = __builtin_amdgcn_mfma_f32_16x16x32_bf16(
              af[m][ks], bfr[n][ks], acc[m][n], 0, 0, 0);
    __syncthreads();
  }

  const int rbase = bm + wm * 64 + (lane >> 4) * 4;
#pragma unroll
  for (int m = 0; m < 4; ++m)
#pragma unroll
    for (int n = 0; n < 2; ++n) {
      const int col = bn + wn * 32 + n * 16 + r15;
#pragma unroll
      for (int r = 0; r < 4; ++r)
        C[(size_t)(rbase + m * 16 + r) * 1024 + col] = acc[m][n][r];
    }
}

// ---------- prep: blocks 0..4095 transpose W_z -> bf16; 4096..12287 cvt X ----
__global__ __launch_bounds__(256) void prep(const float* __restrict__ X,
                                            const float* __restrict__ Wq,
                                            const float* __restrict__ Wf,
                                            const float* __restrict__ Wi,
                                            const float* __restrict__ Wo,
                                            __hip_bfloat16* __restrict__ Xb,
                                            __hip_bfloat16* __restrict__ Wall) {
  const int blk = blockIdx.x;
  if (blk < 4096) {
    const int z = blk >> 10;
    const int idx = blk & 1023;
    const float* W = z == 0 ? Wq : z == 1 ? Wf : z == 2 ? Wi : Wo;
    __hip_bfloat16* Wt = Wall + (size_t)z * 1024 * 1024;
    __shared__ __hip_bfloat16 t[32][33];
    const int bx = (idx & 31) << 5, by = (idx >> 5) << 5;
    const int tx = threadIdx.x & 31, ty = threadIdx.x >> 5;
#pragma unroll
    for (int i = 0; i < 4; ++i)
      t[ty + 8 * i][tx] = __float2bfloat16(W[(size_t)(by + ty + 8 * i) * 1024 + bx + tx]);
    __syncthreads();
#pragma unroll
    for (int i = 0; i < 4; ++i)
      Wt[(size_t)(bx + ty + 8 * i) * 1024 + by + tx] = t[tx][ty + 8 * i];
  } else {
    const size_t i = ((size_t)(blk - 4096) * 256 + threadIdx.x) * 4;
    float4 v = *reinterpret_cast<const float4*>(X + i);
    __hip_bfloat16 o4[4] = {__float2bfloat16(v.x), __float2bfloat16(v.y),
                            __float2bfloat16(v.z), __float2bfloat16(v.w)};
    *reinterpret_cast<uint2*>(Xb + i) = *reinterpret_cast<uint2*>(o4);
  }
}

// ---- DPP reductions ----
__device__ inline float wave_sum64(float x) {
  x += __int_as_float(__builtin_amdgcn_update_dpp(0, __float_as_int(x), 0xB1, 0xf, 0xf, true));
  x += __int_as_float(__builtin_amdgcn_update_dpp(0, __float_as_int(x), 0x4E, 0xf, 0xf, true));
  x += __int_as_float(__builtin_amdgcn_update_dpp(0, __float_as_int(x), 0x141, 0xf, 0xf, true));
  x += __int_as_float(__builtin_amdgcn_update_dpp(0, __float_as_int(x), 0x140, 0xf, 0xf, true));
  x += __int_as_float(__builtin_amdgcn_update_dpp(0, __float_as_int(x), 0x142, 0xa, 0xf, false));
  x += __int_as_float(__builtin_amdgcn_update_dpp(0, __float_as_int(x), 0x143, 0xc, 0xf, false));
  return __int_as_float(__builtin_amdgcn_readlane(__float_as_int(x), 63));
}
__device__ inline float wave_max64(float x) {
  x = fmaxf(x, __int_as_float(__builtin_amdgcn_update_dpp(0, __float_as_int(x), 0xB1, 0xf, 0xf, true)));
  x = fmaxf(x, __int_as_float(__builtin_amdgcn_update_dpp(0, __float_as_int(x), 0x4E, 0xf, 0xf, true)));
  x = fmaxf(x, __int_as_float(__builtin_amdgcn_update_dpp(0, __float_as_int(x), 0x141, 0xf, 0xf, true)));
  x = fmaxf(x, __int_as_float(__builtin_amdgcn_update_dpp(0, __float_as_int(x), 0x140, 0xf, 0xf, true)));
  x = fmaxf(x, __int_as_float(__builtin_amdgcn_update_dpp(0, __float_as_int(x), 0x142, 0xa, 0xf, false)));
  x = fmaxf(x, __int_as_float(__builtin_amdgcn_update_dpp(0, __float_as_int(x), 0x143, 0xc, 0xf, false)));
  return __int_as_float(__builtin_amdgcn_readlane(__float_as_int(x), 63));
}
// 16-lane butterfly sum: every lane ends with the sum of its 16-lane group.
__device__ inline float grp16_sum(float x) {
  x += __int_as_float(__builtin_amdgcn_update_dpp(0, __float_as_int(x), 0xB1, 0xf, 0xf, true));
  x += __int_as_float(__builtin_amdgcn_update_dpp(0, __float_as_int(x), 0x4E, 0xf, 0xf, true));
  x += __int_as_float(__builtin_amdgcn_update_dpp(0, __float_as_int(x), 0x141, 0xf, 0xf, true));
  x += __int_as_float(__builtin_amdgcn_update_dpp(0, __float_as_int(x), 0x140, 0xf, 0xf, true));
  return x;
}

// One block per row: q slice (softmax * 0.125) AND f slice (e = softmax(f)),
// both in place. __expf + rcp.
__global__ __launch_bounds__(256) void rowsoft2(__hip_bfloat16* __restrict__ qfv) {
  const int row = blockIdx.x;
  const int tid = threadIdx.x;
  const int wv = tid >> 6;
  __hip_bfloat16* pq = qfv + (size_t)row * 3072;
  __hip_bfloat16* pf = pq + 1024;
  ushort4 uq = reinterpret_cast<ushort4*>(pq)[tid];
  ushort4 uf = reinterpret_cast<ushort4*>(pf)[tid];
  float q0 = __uint_as_float((unsigned)uq.x << 16), q1 = __uint_as_float((unsigned)uq.y << 16);
  float q2 = __uint_as_float((unsigned)uq.z << 16), q3 = __uint_as_float((unsigned)uq.w << 16);
  float f0 = __uint_as_float((unsigned)uf.x << 16), f1 = __uint_as_float((unsigned)uf.y << 16);
  float f2 = __uint_as_float((unsigned)uf.z << 16), f3 = __uint_as_float((unsigned)uf.w << 16);

  float mq = wave_max64(fmaxf(fmaxf(q0, q1), fmaxf(q2, q3)));
  float mf = wave_max64(fmaxf(fmaxf(f0, f1), fmaxf(f2, f3)));
  __shared__ float red[4][8];
  if ((tid & 63) == 0) { red[wv][0] = mq; red[wv][1] = mf; }
  __syncthreads();
  mq = fmaxf(fmaxf(red[0][0], red[1][0]), fmaxf(red[2][0], red[3][0]));
  mf = fmaxf(fmaxf(red[0][1], red[1][1]), fmaxf(red[2][1], red[3][1]));

  float eq0 = __expf(q0 - mq), eq1 = __expf(q1 - mq), eq2 = __expf(q2 - mq), eq3 = __expf(q3 - mq);
  float ef0 = __expf(f0 - mf), ef1 = __expf(f1 - mf), ef2 = __expf(f2 - mf), ef3 = __expf(f3 - mf);
  float sq = wave_sum64(eq0 + eq1 + eq2 + eq3);
  float sf = wave_sum64(ef0 + ef1 + ef2 + ef3);
  if ((tid & 63) == 0) { red[wv][2] = sq; red[wv][3] = sf; }
  __syncthreads();
  sq = red[0][2] + red[1][2] + red[2][2] + red[3][2];
  sf = red[0][3] + red[1][3] + red[2][3] + red[3][3];

  const float iq = 0.125f * __builtin_amdgcn_rcpf(sq);
  const float iff = __builtin_amdgcn_rcpf(sf);
  __hip_bfloat16 oq[4] = {__float2bfloat16(eq0 * iq), __float2bfloat16(eq1 * iq),
                          __float2bfloat16(eq2 * iq), __float2bfloat16(eq3 * iq)};
  __hip_bfloat16 of[4] = {__float2bfloat16(ef0 * iff), __float2bfloat16(ef1 * iff),
                          __float2bfloat16(ef2 * iff), __float2bfloat16(ef3 * iff)};
  reinterpret_cast<ushort4*>(pq)[tid] = *reinterpret_cast<ushort4*>(oq);
  reinterpret_cast<ushort4*>(pf)[tid] = *reinterpret_cast<ushort4*>(of);
}

// ---------- windowed GLA recurrence, vectorized (verified r14) ----------
__global__ __launch_bounds__(256) void gla_recur(const __hip_bfloat16* __restrict__ qfv,
                                                 __hip_bfloat16* __restrict__ o) {
  const int w = blockIdx.x * 4 + (threadIdx.x >> 6);
  const int lane = threadIdx.x & 63;
  const int row = w >> 2;            // b*2048 + t
  const int hg = w & 3;
  const int t = row & 2047;
  const int jmax = t < WIN ? t : WIN;
  const size_t off = (size_t)hg * 256 + lane * 4;

  ushort4 uq = *reinterpret_cast<const ushort4*>(qfv + (size_t)row * 3072 + off);
  float q[4] = {__uint_as_float((unsigned)uq.x << 16), __uint_as_float((unsigned)uq.y << 16),
                __uint_as_float((unsigned)uq.z << 16), __uint_as_float((unsigned)uq.w << 16)};
  float e[WIN + 1][4], vv[WIN + 1][4];
#pragma unroll
  for (int j = 0; j <= WIN; ++j) {
    const int rj = (j <= jmax) ? row - j : row;
    ushort4 ue = *reinterpret_cast<const ushort4*>(qfv + (size_t)rj * 3072 + 1024 + off);
    ushort4 uv = *reinterpret_cast<const ushort4*>(qfv + (size_t)rj * 3072 + 2048 + off);
    e[j][0] = __uint_as_float((unsigned)ue.x << 16);
    e[j][1] = __uint_as_float((unsigned)ue.y << 16);
    e[j][2] = __uint_as_float((unsigned)ue.z << 16);
    e[j][3] = __uint_as_float((unsigned)ue.w << 16);
    vv[j][0] = __uint_as_float((unsigned)uv.x << 16);
    vv[j][1] = __uint_as_float((unsigned)uv.y << 16);
    vv[j][2] = __uint_as_float((unsigned)uv.z << 16);
    vv[j][3] = __uint_as_float((unsigned)uv.w << 16);
  }
  float d[4] = {1.0f, 1.0f, 1.0f, 1.0f};
  float pr[WIN + 1];
#pragma unroll
  for (int j = 0; j <= WIN; ++j) {
    float s = 0.0f;
#pragma unroll
    for (int i = 0; i < 4; ++i) {
      s = fmaf(q[i] * d[i], 1.0f - e[j][i], s);
      d[i] *= e[j][i];
    }
    pr[j] = (j <= jmax) ? s : 0.0f;
  }
#pragma unroll
  for (int j = 0; j <= WIN; ++j) pr[j] = grp16_sum(pr[j]);
  float acc[4] = {};
#pragma unroll
  for (int j = 0; j <= WIN; ++j)
#pragma unroll
    for (int i = 0; i < 4; ++i) acc[i] = fmaf(pr[j], vv[j][i], acc[i]);
  __hip_bfloat16 o4[4] = {__float2bfloat16(acc[0]), __float2bfloat16(acc[1]),
                          __float2bfloat16(acc[2]), __float2bfloat16(acc[3])};
  *reinterpret_cast<uint2*>(o + (size_t)row * 1024 + off) = *reinterpret_cast<uint2*>(o4);
}

extern "C" void kernel_launch(void* const* d_in, const int* in_sizes, int n_in,
                              void* d_out, int out_size, void* d_ws, size_t ws_size,
                              hipStream_t stream) {
  const float* X  = (const float*)d_in[0];
  const float* Wq = (const float*)d_in[1];
  const float* Wf = (const float*)d_in[2];
  const float* Wi = (const float*)d_in[3];
  const float* Wo = (const float*)d_in[4];
  float* out = (float*)d_out;

  __hip_bfloat16* qfv = (__hip_bfloat16*)d_ws;       // [8192][3072] bf16
  __hip_bfloat16* Xb  = qfv + (size_t)8192 * 3072;   // 16 MiB
  __hip_bfloat16* Wall = Xb + NE;                    // [4][1024][1024] bf16
  __hip_bfloat16* ob  = Xb;  // alias: Xb dead after QFV GEMM

  prep<<<12288, 256, 0, stream>>>(X, Wq, Wf, Wi, Wo, Xb, Wall);
  gemm_sb<<<dim3(24, 32), 512, 0, stream>>>(Xb, Wall, qfv, 1024);
  rowsoft2<<<8192, 256, 0, stream>>>(qfv);
  gla_recur<<<8192, 256, 0, stream>>>(qfv, ob);
  gemm_out8<<<dim3(8, 64), 512, 0, stream>>>(ob, Wall + (size_t)3 * 1024 * 1024,
                                             out, 1024);
}

// Round 16
// 117.498 us; speedup vs baseline: 1.2032x; 1.2032x over previous
//
#include <hip/hip_runtime.h>
#include <hip/hip_bf16.h>

// GLA forward, B=4 L=2048 D=1024 H=16 DK=DV=64.
// Round 16: chunked soft_recur fusion — each block owns 16 rows of one batch;
// f-softmax for its 21-row window (5-row halo, 31% redundancy, vs r13's 500%)
// into LDS bf16; q-softmax + recurrence wave-local (lane owns cols 16l+4i+c,
// head reduction = in-lane 16 + DPP quad sum). Removes the 64MB q/e round
// trip + one launch. GEMMs and prep identical to r15/r14.

typedef __attribute__((ext_vector_type(8))) short s16x8;
typedef __attribute__((ext_vector_type(4))) float f32x4;

#define WIN 5
static const size_t NE = (size_t)8192 * 1024;

__device__ inline void gload16(const void* g, void* lds) {
  __builtin_amdgcn_global_load_lds(
      (const __attribute__((address_space(1))) unsigned int*)g,
      (__attribute__((address_space(3))) unsigned int*)lds, 16, 0, 0);
}

// ---------- QFV: 256x128, BK=64, 8 waves (4M x 2N), SINGLE buffer ----------
// (verified r11-r15: 59.5us, 872 TF, zero bank conflicts, clean traffic)
__global__ __launch_bounds__(512, 2) void gemm_sb(
    const __hip_bfloat16* __restrict__ A, const __hip_bfloat16* __restrict__ Bt,
    __hip_bfloat16* __restrict__ Obf, int K) {
  __shared__ __hip_bfloat16 sa[256 * 64];  // 32 KiB
  __shared__ __hip_bfloat16 sb[128 * 64];  // 16 KiB
  const int tid = threadIdx.x;
  const int lane = tid & 63;
  const int w = tid >> 6;
  const int wm = w >> 1, wn = w & 1;
  const int bm = blockIdx.y * 256, bn = blockIdx.x * 128;

  const int srow = tid >> 3;
  const int scol = ((tid & 7) ^ (srow & 7)) * 8;
  const int r15 = lane & 15, g = lane >> 4;
  const int rx = (r15 & 7) << 4;

  f32x4 acc[4][4] = {};
  const int NT = K / 64;
  for (int t = 0; t < NT; ++t) {
    const int bk = t * 64;
#pragma unroll
    for (int r = 0; r < 4; ++r)
      gload16(A + (size_t)(bm + r * 64 + srow) * K + bk + scol,
              &sa[r * 4096 + tid * 8]);
#pragma unroll
    for (int r = 0; r < 2; ++r)
      gload16(Bt + (size_t)(bn + r * 64 + srow) * K + bk + scol,
              &sb[r * 4096 + tid * 8]);
    __syncthreads();
    s16x8 bfr[4][2], af[4][2];
#pragma unroll
    for (int n = 0; n < 4; ++n)
#pragma unroll
      for (int ks = 0; ks < 2; ++ks)
        bfr[n][ks] = *(const s16x8*)((const char*)sb + (wn * 64 + n * 16 + r15) * 128 +
                                     ((g * 16 + ks * 64) ^ rx));
#pragma unroll
    for (int m = 0; m < 4; ++m)
#pragma unroll
      for (int ks = 0; ks < 2; ++ks)
        af[m][ks] = *(const s16x8*)((const char*)sa + (wm * 64 + m * 16 + r15) * 128 +
                                    ((g * 16 + ks * 64) ^ rx));
#pragma unroll
    for (int m = 0; m < 4; ++m)
#pragma unroll
      for (int n = 0; n < 4; ++n)
#pragma unroll
        for (int ks = 0; ks < 2; ++ks)
          acc[m][n] = __builtin_amdgcn_mfma_f32_16x16x32_bf16(
              af[m][ks], bfr[n][ks], acc[m][n], 0, 0, 0);
    __syncthreads();
  }

  const int rbase = bm + wm * 64 + (lane >> 4) * 4;
#pragma unroll
  for (int m = 0; m < 4; ++m)
#pragma unroll
    for (int n = 0; n < 4; ++n) {
      const int col = bn + wn * 64 + n * 16 + r15;
#pragma unroll
      for (int r = 0; r < 4; ++r)
        Obf[(size_t)(rbase + m * 16 + r) * 3072 + col] = __float2bfloat16(acc[m][n][r]);
    }
}

// ---------- out projection: 128x128, BK=64, 8 waves (2M x 4N), 1 buffer ----
__global__ __launch_bounds__(512, 2) void gemm_out8(
    const __hip_bfloat16* __restrict__ A, const __hip_bfloat16* __restrict__ Bt,
    float* __restrict__ C, int K) {
  __shared__ __hip_bfloat16 sa[128 * 64];
  __shared__ __hip_bfloat16 sb[128 * 64];
  const int tid = threadIdx.x;
  const int lane = tid & 63;
  const int w = tid >> 6;
  const int wm = w >> 2, wn = w & 3;
  const int bm = blockIdx.y * 128, bn = blockIdx.x * 128;

  const int srow = tid >> 3;
  const int scol = ((tid & 7) ^ (srow & 7)) * 8;
  const int r15 = lane & 15, g = lane >> 4;
  const int rx = (r15 & 7) << 4;

  f32x4 acc[4][2] = {};
  const int NT = K / 64;
  for (int t = 0; t < NT; ++t) {
    const int bk = t * 64;
#pragma unroll
    for (int r = 0; r < 2; ++r)
      gload16(A + (size_t)(bm + r * 64 + srow) * K + bk + scol,
              &sa[r * 4096 + tid * 8]);
#pragma unroll
    for (int r = 0; r < 2; ++r)
      gload16(Bt + (size_t)(bn + r * 64 + srow) * K + bk + scol,
              &sb[r * 4096 + tid * 8]);
    __syncthreads();
    s16x8 bfr[2][2], af[4][2];
#pragma unroll
    for (int n = 0; n < 2; ++n)
#pragma unroll
      for (int ks = 0; ks < 2; ++ks)
        bfr[n][ks] = *(const s16x8*)((const char*)sb + (wn * 32 + n * 16 + r15) * 128 +
                                     ((g * 16 + ks * 64) ^ rx));
#pragma unroll
    for (int m = 0; m < 4; ++m)
#pragma unroll
      for (int ks = 0; ks < 2; ++ks)
        af[m][ks] = *(const s16x8*)((const char*)sa + (wm * 64 + m * 16 + r15) * 128 +
                                    ((g * 16 + ks * 64) ^ rx));
#pragma unroll
    for (int m = 0; m < 4; ++m)
#pragma unroll
      for (int n = 0; n < 2; ++n)
#pragma unroll
        for (int ks = 0; ks < 2; ++ks)
          acc[m][n] = __builtin_amdgcn_mfma_f32_16x16x32_bf16(
              af[m][ks], bfr[n][ks], acc[m][n], 0, 0, 0);
    __syncthreads();
  }

  const int rbase = bm + wm * 64 + (lane >> 4) * 4;
#pragma unroll
  for (int m = 0; m < 4; ++m)
#pragma unroll
    for (int n = 0; n < 2; ++n) {
      const int col = bn + wn * 32 + n * 16 + r15;
#pragma unroll
      for (int r = 0; r < 4; ++r)
        C[(size_t)(rbase + m * 16 + r) * 1024 + col] = acc[m][n][r];
    }
}

// ---------- prep: blocks 0..4095 transpose W_z -> bf16; 4096..12287 cvt X ----
__global__ __launch_bounds__(256) void prep(const float* __restrict__ X,
                                            const float* __restrict__ Wq,
                                            const float* __restrict__ Wf,
                                            const float* __restrict__ Wi,
                                            const float* __restrict__ Wo,
                                            __hip_bfloat16* __restrict__ Xb,
                                            __hip_bfloat16* __restrict__ Wall) {
  const int blk = blockIdx.x;
  if (blk < 4096) {
    const int z = blk >> 10;
    const int idx = blk & 1023;
    const float* W = z == 0 ? Wq : z == 1 ? Wf : z == 2 ? Wi : Wo;
    __hip_bfloat16* Wt = Wall + (size_t)z * 1024 * 1024;
    __shared__ __hip_bfloat16 t[32][33];
    const int bx = (idx & 31) << 5, by = (idx >> 5) << 5;
    const int tx = threadIdx.x & 31, ty = threadIdx.x >> 5;
#pragma unroll
    for (int i = 0; i < 4; ++i)
      t[ty + 8 * i][tx] = __float2bfloat16(W[(size_t)(by + ty + 8 * i) * 1024 + bx + tx]);
    __syncthreads();
#pragma unroll
    for (int i = 0; i < 4; ++i)
      Wt[(size_t)(bx + ty + 8 * i) * 1024 + by + tx] = t[tx][ty + 8 * i];
  } else {
    const size_t i = ((size_t)(blk - 4096) * 256 + threadIdx.x) * 4;
    float4 v = *reinterpret_cast<const float4*>(X + i);
    __hip_bfloat16 o4[4] = {__float2bfloat16(v.x), __float2bfloat16(v.y),
                            __float2bfloat16(v.z), __float2bfloat16(v.w)};
    *reinterpret_cast<uint2*>(Xb + i) = *reinterpret_cast<uint2*>(o4);
  }
}

// ---- DPP reductions ----
__device__ inline float wave_sum64(float x) {
  x += __int_as_float(__builtin_amdgcn_update_dpp(0, __float_as_int(x), 0xB1, 0xf, 0xf, true));
  x += __int_as_float(__builtin_amdgcn_update_dpp(0, __float_as_int(x), 0x4E, 0xf, 0xf, true));
  x += __int_as_float(__builtin_amdgcn_update_dpp(0, __float_as_int(x), 0x141, 0xf, 0xf, true));
  x += __int_as_float(__builtin_amdgcn_update_dpp(0, __float_as_int(x), 0x140, 0xf, 0xf, true));
  x += __int_as_float(__builtin_amdgcn_update_dpp(0, __float_as_int(x), 0x142, 0xa, 0xf, false));
  x += __int_as_float(__builtin_amdgcn_update_dpp(0, __float_as_int(x), 0x143, 0xc, 0xf, false));
  return __int_as_float(__builtin_amdgcn_readlane(__float_as_int(x), 63));
}
__device__ inline float wave_max64(float x) {
  x = fmaxf(x, __int_as_float(__builtin_amdgcn_update_dpp(0, __float_as_int(x), 0xB1, 0xf, 0xf, true)));
  x = fmaxf(x, __int_as_float(__builtin_amdgcn_update_dpp(0, __float_as_int(x), 0x4E, 0xf, 0xf, true)));
  x = fmaxf(x, __int_as_float(__builtin_amdgcn_update_dpp(0, __float_as_int(x), 0x141, 0xf, 0xf, true)));
  x = fmaxf(x, __int_as_float(__builtin_amdgcn_update_dpp(0, __float_as_int(x), 0x140, 0xf, 0xf, true)));
  x = fmaxf(x, __int_as_float(__builtin_amdgcn_update_dpp(0, __float_as_int(x), 0x142, 0xa, 0xf, false)));
  x = fmaxf(x, __int_as_float(__builtin_amdgcn_update_dpp(0, __float_as_int(x), 0x143, 0xc, 0xf, false)));
  return __int_as_float(__builtin_amdgcn_readlane(__float_as_int(x), 63));
}
// quad (4-lane) sum: all lanes of each quad end with the quad's sum.
__device__ inline float quad_sum(float x) {
  x += __int_as_float(__builtin_amdgcn_update_dpp(0, __float_as_int(x), 0xB1, 0xf, 0xf, true));
  x += __int_as_float(__builtin_amdgcn_update_dpp(0, __float_as_int(x), 0x4E, 0xf, 0xf, true));
  return x;
}

__device__ inline float bf2f_u(unsigned short u) {
  return __uint_as_float((unsigned)u << 16);
}

// ---------- fused softmax + windowed recurrence (chunked, 16 rows/block) ----
// Lane l owns cols {16l+4i+c}. LDS e layout: slot s, byte (i*64+lane)*8 holds
// bf16x4 of cols 16l+4i.. — conflict-free write & read. Head h = l>>2; the
// per-head k-reduction = in-lane sum of 16 + DPP quad sum (quads == heads).
__global__ __launch_bounds__(256) void soft_recur(const __hip_bfloat16* __restrict__ qfv,
                                                  __hip_bfloat16* __restrict__ o) {
  __shared__ __hip_bfloat16 e_lds[21][1024];
  const int blk = blockIdx.x;
  const int batch = blk >> 7, chunk = blk & 127;
  const int t0 = chunk << 4;
  const int r0 = (batch << 11) + t0;
  const int tid = threadIdx.x;
  const int wv = tid >> 6, lane = tid & 63;

  // ---- phase 1: e = softmax(f) for slots 0..20 (rows r0-5..r0+15, clamped)
  for (int s = wv; s < 21; s += 4) {
    const int tr = t0 + s - 5;
    const int row = r0 + (tr < 0 ? 0 : s - 5);  // clamped rows are masked later
    float f[16];
    float mx = -1e30f;
#pragma unroll
    for (int i = 0; i < 4; ++i) {
      ushort4 u = *reinterpret_cast<const ushort4*>(
          qfv + (size_t)row * 3072 + 1024 + lane * 16 + i * 4);
      f[4 * i + 0] = bf2f_u(u.x); f[4 * i + 1] = bf2f_u(u.y);
      f[4 * i + 2] = bf2f_u(u.z); f[4 * i + 3] = bf2f_u(u.w);
    }
#pragma unroll
    for (int k = 0; k < 16; ++k) mx = fmaxf(mx, f[k]);
    mx = wave_max64(mx);
    float sm = 0.0f;
#pragma unroll
    for (int k = 0; k < 16; ++k) { f[k] = __expf(f[k] - mx); sm += f[k]; }
    sm = wave_sum64(sm);
    const float inv = __builtin_amdgcn_rcpf(sm);
#pragma unroll
    for (int i = 0; i < 4; ++i) {
      __hip_bfloat16 e4[4] = {
          __float2bfloat16(f[4 * i + 0] * inv), __float2bfloat16(f[4 * i + 1] * inv),
          __float2bfloat16(f[4 * i + 2] * inv), __float2bfloat16(f[4 * i + 3] * inv)};
      *reinterpret_cast<uint2*>(
          reinterpret_cast<char*>(&e_lds[s][0]) + (i * 64 + lane) * 8) =
          *reinterpret_cast<uint2*>(e4);
    }
  }
  __syncthreads();

  // ---- phase 2: q-softmax + recurrence, 4 rows per wave ----
  for (int rr = wv; rr < 16; rr += 4) {
    const int row = r0 + rr;
    const int t = t0 + rr;
    const int jmax = t < WIN ? t : WIN;
    float q[16];
    float mx = -1e30f;
#pragma unroll
    for (int i = 0; i < 4; ++i) {
      ushort4 u = *reinterpret_cast<const ushort4*>(
          qfv + (size_t)row * 3072 + lane * 16 + i * 4);
      q[4 * i + 0] = bf2f_u(u.x); q[4 * i + 1] = bf2f_u(u.y);
      q[4 * i + 2] = bf2f_u(u.z); q[4 * i + 3] = bf2f_u(u.w);
    }
#pragma unroll
    for (int k = 0; k < 16; ++k) mx = fmaxf(mx, q[k]);
    mx = wave_max64(mx);
    float sm = 0.0f;
#pragma unroll
    for (int k = 0; k < 16; ++k) { q[k] = __expf(q[k] - mx); sm += q[k]; }
    sm = wave_sum64(sm);
    const float qs = 0.125f * __builtin_amdgcn_rcpf(sm);
#pragma unroll
    for (int k = 0; k < 16; ++k) q[k] *= qs;

    float d[16], acc[16] = {};
#pragma unroll
    for (int k = 0; k < 16; ++k) d[k] = 1.0f;
#pragma unroll
    for (int j = 0; j <= WIN; ++j) {
      const int s = rr + 5 - j;
      float e[16];
#pragma unroll
      for (int i = 0; i < 4; ++i) {
        uint2 u = *reinterpret_cast<const uint2*>(
            reinterpret_cast<const char*>(&e_lds[s][0]) + (i * 64 + lane) * 8);
        const unsigned short* us = reinterpret_cast<const unsigned short*>(&u);
        e[4 * i + 0] = bf2f_u(us[0]); e[4 * i + 1] = bf2f_u(us[1]);
        e[4 * i + 2] = bf2f_u(us[2]); e[4 * i + 3] = bf2f_u(us[3]);
      }
      float p = 0.0f;
#pragma unroll
      for (int k = 0; k < 16; ++k) {
        p = fmaf(q[k] * d[k], 1.0f - e[k], p);
        d[k] *= e[k];
      }
      p = (j <= jmax) ? p : 0.0f;
      p = quad_sum(p);  // head = lane>>2: quad == head
      const int rj = (j <= jmax) ? row - j : row;
#pragma unroll
      for (int i = 0; i < 4; ++i) {
        ushort4 uv = *reinterpret_cast<const ushort4*>(
            qfv + (size_t)rj * 3072 + 2048 + lane * 16 + i * 4);
        acc[4 * i + 0] = fmaf(p, bf2f_u(uv.x), acc[4 * i + 0]);
        acc[4 * i + 1] = fmaf(p, bf2f_u(uv.y), acc[4 * i + 1]);
        acc[4 * i + 2] = fmaf(p, bf2f_u(uv.z), acc[4 * i + 2]);
        acc[4 * i + 3] = fmaf(p, bf2f_u(uv.w), acc[4 * i + 3]);
      }
    }
#pragma unroll
    for (int i = 0; i < 4; ++i) {
      __hip_bfloat16 o4[4] = {__float2bfloat16(acc[4 * i + 0]), __float2bfloat16(acc[4 * i + 1]),
                              __float2bfloat16(acc[4 * i + 2]), __float2bfloat16(acc[4 * i + 3])};
      *reinterpret_cast<uint2*>(o + (size_t)row * 1024 + lane * 16 + i * 4) =
          *reinterpret_cast<uint2*>(o4);
    }
  }
}

extern "C" void kernel_launch(void* const* d_in, const int* in_sizes, int n_in,
                              void* d_out, int out_size, void* d_ws, size_t ws_size,
                              hipStream_t stream) {
  const float* X  = (const float*)d_in[0];
  const float* Wq = (const float*)d_in[1];
  const float* Wf = (const float*)d_in[2];
  const float* Wi = (const float*)d_in[3];
  const float* Wo = (const float*)d_in[4];
  float* out = (float*)d_out;

  __hip_bfloat16* qfv = (__hip_bfloat16*)d_ws;       // [8192][3072] bf16
  __hip_bfloat16* Xb  = qfv + (size_t)8192 * 3072;   // 16 MiB
  __hip_bfloat16* Wall = Xb + NE;                    // [4][1024][1024] bf16
  __hip_bfloat16* ob  = Xb;  // alias: Xb dead after QFV GEMM

  prep<<<12288, 256, 0, stream>>>(X, Wq, Wf, Wi, Wo, Xb, Wall);
  gemm_sb<<<dim3(24, 32), 512, 0, stream>>>(Xb, Wall, qfv, 1024);
  soft_recur<<<512, 256, 0, stream>>>(qfv, ob);
  gemm_out8<<<dim3(8, 64), 512, 0, stream>>>(ob, Wall + (size_t)3 * 1024 * 1024,
                                             out, 1024);
}